// Round 1
// baseline (8926.552 us; speedup 1.0000x reference)
//
#include <hip/hip_runtime.h>
#include <math.h>

// forecastRNN: B=512 batch, 64 RNN steps over F=512 feats, 3-layer BN autoenc
// (512->1000->1000->512) on all hidden states, MSE loss, 16-step decode with
// per-batch gap selection. fp32 correctness-first baseline; GEMMs are generic
// NT tiled (64x64 tile, 4x4/thread) with fused epilogues.

#define BB 512
#define TT 65
#define TN 64
#define FF 512
#define HD 1000
#define EPSBN 1e-5f
#define BF (BB*FF)          // 262144
#define BTF (BB*TN*FF)      // 16777216
#define TILE 64
#define KT 16
#define BIGDIV (1<<30)

// epi codes:
// 0: out = acc + p1[n] + p2[n]                      (XW precompute)
// 1: out = tanh(acc + out[m,n])                     (recurrence, in-place over XW)
// 2: out = (acc + p1[n] - rm[n]) * (g[n]*rsqrt(rv[n]+eps)) + be[n]   (BN)
// 3: out = tanh(acc + p1[n] + p2[n])                (decode cell, DUAL)
__global__ __launch_bounds__(256)
void gemm_nt(const float* __restrict__ A, int adiv, long as1, long as2,
             const float* __restrict__ A2, long a2s,
             const float* __restrict__ W, const float* __restrict__ W2,
             float* __restrict__ out, long ostride,
             int M, int N, int K, int K2,
             int epi,
             const float* __restrict__ p1, const float* __restrict__ p2,
             const float* __restrict__ rm, const float* __restrict__ rv,
             const float* __restrict__ gg, const float* __restrict__ be)
{
    __shared__ float As[KT][TILE + 4];
    __shared__ float Ws[KT][TILE + 4];
    const int tid = threadIdx.x;
    const int tx = tid & 15, ty = tid >> 4;
    const int bm = blockIdx.y, bn = blockIdx.x;
    const int ldr = tid >> 2;          // 0..63: row within tile for staging
    const int ldk = (tid & 3) << 2;    // 0,4,8,12: k offset for staging

    const int gar = bm * TILE + ldr;   // M is always a multiple of 64 here
    const float* arow = A + (size_t)(gar / adiv) * as1 + (size_t)(gar % adiv) * as2;
    const float* a2row = A2 ? (A2 + (size_t)gar * a2s) : nullptr;
    const int gwr = bn * TILE + ldr;
    const float* wrow  = (gwr < N) ? (W + (size_t)gwr * K) : nullptr;
    const float* w2row = (A2 && gwr < N) ? (W2 + (size_t)gwr * K2) : nullptr;

    float acc[4][4];
#pragma unroll
    for (int i = 0; i < 4; ++i)
#pragma unroll
        for (int j = 0; j < 4; ++j) acc[i][j] = 0.f;

    const int npass = A2 ? 2 : 1;
    for (int pass = 0; pass < npass; ++pass) {
        const float* ar = pass ? a2row : arow;
        const float* wr = pass ? w2row : wrow;
        const int Kc = pass ? K2 : K;
        for (int kt = 0; kt < Kc; kt += KT) {
            __syncthreads();
            const int k = kt + ldk;
            float4 av = make_float4(0.f, 0.f, 0.f, 0.f);
            float4 wv = make_float4(0.f, 0.f, 0.f, 0.f);
            if (k < Kc) {                       // K is always a multiple of 4
                av = *(const float4*)(ar + k);
                if (wr) wv = *(const float4*)(wr + k);
            }
            As[ldk + 0][ldr] = av.x; As[ldk + 1][ldr] = av.y;
            As[ldk + 2][ldr] = av.z; As[ldk + 3][ldr] = av.w;
            Ws[ldk + 0][ldr] = wv.x; Ws[ldk + 1][ldr] = wv.y;
            Ws[ldk + 2][ldr] = wv.z; Ws[ldk + 3][ldr] = wv.w;
            __syncthreads();
#pragma unroll
            for (int kk = 0; kk < KT; ++kk) {
                float4 a4 = *(const float4*)&As[kk][ty << 2];
                float4 w4 = *(const float4*)&Ws[kk][tx << 2];
                float aa[4] = {a4.x, a4.y, a4.z, a4.w};
                float ww[4] = {w4.x, w4.y, w4.z, w4.w};
#pragma unroll
                for (int i = 0; i < 4; ++i)
#pragma unroll
                    for (int j = 0; j < 4; ++j)
                        acc[i][j] += aa[i] * ww[j];
            }
        }
    }

    const int rowbase = bm * TILE + (ty << 2);
    const int colbase = bn * TILE + (tx << 2);
#pragma unroll
    for (int i = 0; i < 4; ++i) {
        float* orow = out + (size_t)(rowbase + i) * ostride;
#pragma unroll
        for (int j = 0; j < 4; ++j) {
            const int n = colbase + j;
            if (n < N) {
                float v = acc[i][j];
                if (epi == 0) {
                    v = v + p1[n] + p2[n];
                } else if (epi == 1) {
                    v = tanhf(v + orow[n]);
                } else if (epi == 2) {
                    float s = gg[n] * (1.f / sqrtf(rv[n] + EPSBN));
                    v = (v + p1[n] - rm[n]) * s + be[n];
                } else {
                    v = tanhf(v + p1[n] + p2[n]);
                }
                orow[n] = v;
            }
        }
    }
}

// t=0 recurrence step (h0 = 0): hs[b,0,:] = tanh(XW[b,0,:]); also zero sums.
__global__ void tanh0_init(float* __restrict__ hs, float* __restrict__ sums)
{
    const int i = blockIdx.x * blockDim.x + threadIdx.x;
    if (i == 0) { sums[0] = 0.f; sums[1] = 0.f; }
    if (i < BF) {
        const int b = i >> 9, f = i & (FF - 1);
        const size_t idx = (size_t)b * (TN * FF) + f;
        hs[idx] = tanhf(hs[idx]);
    }
}

// loss1: sum over (b, tau<63, f) of (y[b,tau,f] - x[b,tau+1,f])^2
__global__ void loss1_kernel(const float* __restrict__ y,
                             const float* __restrict__ x,
                             float* __restrict__ sums)
{
    const int NTOT = BB * 63 * FF;
    float s = 0.f;
    for (int i = blockIdx.x * blockDim.x + threadIdx.x; i < NTOT;
         i += gridDim.x * blockDim.x) {
        const int b = i / (63 * FF);
        const int r = i - b * (63 * FF);
        const int tau = r / FF;
        const int f = r & (FF - 1);
        const float yv = y[((size_t)b * TN + tau) * FF + f];
        const float xv = x[((size_t)b * TT + tau + 1) * FF + f];
        const float d = yv - xv;
        s += d * d;
    }
    __shared__ float red[256];
    red[threadIdx.x] = s;
    __syncthreads();
    for (int o = 128; o > 0; o >>= 1) {
        if (threadIdx.x < o) red[threadIdx.x] += red[threadIdx.x + o];
        __syncthreads();
    }
    if (threadIdx.x == 0) atomicAdd(&sums[0], red[0]);
}

// gather x_pred from xgaps by per-batch gap, write d_out, accumulate loss2 sum
__global__ void gather_kernel(const float* __restrict__ xgaps,
                              const int* __restrict__ tgap,
                              const float* __restrict__ x,
                              float* __restrict__ out,
                              float* __restrict__ sums)
{
    const int i = blockIdx.x * blockDim.x + threadIdx.x;
    float s = 0.f;
    if (i < BF) {
        const int b = i >> 9, f = i & (FF - 1);
        const int g = tgap[b] - 1;
        const float v = xgaps[((size_t)g * BB + b) * FF + f];
        out[i] = v;
        const float d = v - x[((size_t)b * TT + (TT - 1)) * FF + f];
        s = d * d;
    }
    __shared__ float red[256];
    red[threadIdx.x] = s;
    __syncthreads();
    for (int o = 128; o > 0; o >>= 1) {
        if (threadIdx.x < o) red[threadIdx.x] += red[threadIdx.x + o];
        __syncthreads();
    }
    if (threadIdx.x == 0) atomicAdd(&sums[1], red[0]);
}

__global__ void finalize_kernel(const float* __restrict__ sums,
                                float* __restrict__ out)
{
    if (threadIdx.x == 0 && blockIdx.x == 0) {
        const double n1 = 63.0 * 512.0 * 512.0;
        const double n2 = 512.0 * 512.0;
        out[BF] = (float)((double)sums[0] / (n1 * n1) +
                          (double)sums[1] / (n2 * n2));
    }
}

extern "C" void kernel_launch(void* const* d_in, const int* in_sizes, int n_in,
                              void* d_out, int out_size, void* d_ws, size_t ws_size,
                              hipStream_t stream)
{
    const float* x    = (const float*)d_in[0];
    const int*   tgap = (const int*)d_in[1];
    const float* W_ih = (const float*)d_in[2];
    const float* W_hh = (const float*)d_in[3];
    const float* b_ih = (const float*)d_in[4];
    const float* b_hh = (const float*)d_in[5];
    const float* W1 = (const float*)d_in[6];
    const float* b1 = (const float*)d_in[7];
    const float* g1 = (const float*)d_in[8];
    const float* be1 = (const float*)d_in[9];
    const float* rm1 = (const float*)d_in[10];
    const float* rv1 = (const float*)d_in[11];
    const float* W2 = (const float*)d_in[12];
    const float* b2 = (const float*)d_in[13];
    const float* g2 = (const float*)d_in[14];
    const float* be2 = (const float*)d_in[15];
    const float* rm2 = (const float*)d_in[16];
    const float* rv2 = (const float*)d_in[17];
    const float* W3 = (const float*)d_in[18];
    const float* b3 = (const float*)d_in[19];
    const float* g3 = (const float*)d_in[20];
    const float* be3 = (const float*)d_in[21];
    const float* rm3 = (const float*)d_in[22];
    const float* rv3 = (const float*)d_in[23];
    float* out = (float*)d_out;

    // workspace layout (floats): ~222.7 MB total
    float* ws = (float*)d_ws;
    float* hs   = ws;                         // (B,T,F) XW then h      16777216
    float* ybuf = hs + (size_t)BTF;           // (B,T,F) y              16777216
    const int CH = 4, CM = (BB * TN) / CH;    // 4 chunks of 8192 rows
    float* z1c  = ybuf + (size_t)BTF;         // CM*HD                   8192000
    float* z2c  = z1c + (size_t)CM * HD;      // CM*HD                   8192000
    float* xg   = z2c + (size_t)CM * HD;      // (16,B,F)                4194304
    float* zd1  = xg + (size_t)16 * BF;       // B*HD                     512000
    float* zd2  = zd1 + (size_t)BB * HD;      // B*HD                     512000
    float* hdec = zd2 + (size_t)BB * HD;      // 2*(B,F)                  524288
    float* sums = hdec + (size_t)2 * BF;      // 2

    const dim3 blk(256);

    // 1) XW = x[:, :64] @ W_ih^T + b_ih + b_hh  -> hs (B,T,F)
    {
        dim3 grid(FF / TILE, (BB * TN) / TILE);   // 8 x 512
        gemm_nt<<<grid, blk, 0, stream>>>(
            x, TN, (long)TT * FF, FF, nullptr, 0,
            W_ih, nullptr, hs, FF,
            BB * TN, FF, FF, 0, 0,
            b_ih, b_hh, nullptr, nullptr, nullptr, nullptr);
    }
    // 2) t=0: hs[:,0,:] = tanh(XW); init loss sums
    tanh0_init<<<dim3(BF / 256), blk, 0, stream>>>(hs, sums);
    // 3) recurrence t=1..63: hs[:,t,:] = tanh(XW_t + hs[:,t-1,:] @ W_hh^T)
    for (int t = 1; t < TN; ++t) {
        dim3 grid(FF / TILE, BB / TILE);          // 8 x 8
        gemm_nt<<<grid, blk, 0, stream>>>(
            hs + (size_t)(t - 1) * FF, BIGDIV, 0, (long)TN * FF, nullptr, 0,
            W_hh, nullptr, hs + (size_t)t * FF, (long)TN * FF,
            BB, FF, FF, 0, 1,
            nullptr, nullptr, nullptr, nullptr, nullptr, nullptr);
    }
    // 4) autoenc over all 32768 hidden states, in 4 row-chunks
    for (int c = 0; c < CH; ++c) {
        const float* Ac = hs + (size_t)c * CM * FF;
        {   // L1: z1 = BN1(h @ W1^T + b1)
            dim3 grid((HD + TILE - 1) / TILE, CM / TILE);  // 16 x 128
            gemm_nt<<<grid, blk, 0, stream>>>(
                Ac, BIGDIV, 0, FF, nullptr, 0,
                W1, nullptr, z1c, HD,
                CM, HD, FF, 0, 2,
                b1, nullptr, rm1, rv1, g1, be1);
        }
        {   // L2: z2 = BN2(z1 @ W2^T + b2)
            dim3 grid((HD + TILE - 1) / TILE, CM / TILE);
            gemm_nt<<<grid, blk, 0, stream>>>(
                z1c, BIGDIV, 0, HD, nullptr, 0,
                W2, nullptr, z2c, HD,
                CM, HD, HD, 0, 2,
                b2, nullptr, rm2, rv2, g2, be2);
        }
        {   // L3: y = BN3(z2 @ W3^T + b3)
            dim3 grid(FF / TILE, CM / TILE);               // 8 x 128
            gemm_nt<<<grid, blk, 0, stream>>>(
                z2c, BIGDIV, 0, HD, nullptr, 0,
                W3, nullptr, ybuf + (size_t)c * CM * FF, FF,
                CM, FF, HD, 0, 2,
                b3, nullptr, rm3, rv3, g3, be3);
        }
    }
    // 5) loss1 partial sum
    loss1_kernel<<<dim3(2048), blk, 0, stream>>>(ybuf, x, sums);
    // 6) decode: 16 autoregressive steps
    for (int g = 0; g < 16; ++g) {
        const float* xprev = (g == 0) ? (ybuf + (size_t)(TN - 1) * FF)
                                      : (xg + (size_t)(g - 1) * BF);
        const long xstride = (g == 0) ? (long)TN * FF : (long)FF;
        const float* hprev = (g == 0) ? (hs + (size_t)(TN - 1) * FF)
                                      : (hdec + (size_t)((g - 1) & 1) * BF);
        const long hstride = (g == 0) ? (long)TN * FF : (long)FF;
        float* hnew = hdec + (size_t)(g & 1) * BF;
        {   // cell: h2 = tanh(x_hat @ W_ih^T + h_hat @ W_hh^T + b_ih + b_hh)
            dim3 grid(FF / TILE, BB / TILE);
            gemm_nt<<<grid, blk, 0, stream>>>(
                xprev, BIGDIV, 0, xstride, hprev, hstride,
                W_ih, W_hh, hnew, FF,
                BB, FF, FF, FF, 3,
                b_ih, b_hh, nullptr, nullptr, nullptr, nullptr);
        }
        {   // L1
            dim3 grid((HD + TILE - 1) / TILE, BB / TILE);
            gemm_nt<<<grid, blk, 0, stream>>>(
                hnew, BIGDIV, 0, FF, nullptr, 0,
                W1, nullptr, zd1, HD,
                BB, HD, FF, 0, 2,
                b1, nullptr, rm1, rv1, g1, be1);
        }
        {   // L2
            dim3 grid((HD + TILE - 1) / TILE, BB / TILE);
            gemm_nt<<<grid, blk, 0, stream>>>(
                zd1, BIGDIV, 0, HD, nullptr, 0,
                W2, nullptr, zd2, HD,
                BB, HD, HD, 0, 2,
                b2, nullptr, rm2, rv2, g2, be2);
        }
        {   // L3 -> xg slice g
            dim3 grid(FF / TILE, BB / TILE);
            gemm_nt<<<grid, blk, 0, stream>>>(
                zd2, BIGDIV, 0, HD, nullptr, 0,
                W3, nullptr, xg + (size_t)g * BF, FF,
                BB, FF, HD, 0, 2,
                b3, nullptr, rm3, rv3, g3, be3);
        }
    }
    // 7) gather x_pred + loss2 partial sum
    gather_kernel<<<dim3(BF / 256), blk, 0, stream>>>(xg, tgap, x, out, sums);
    // 8) finalize loss scalar
    finalize_kernel<<<dim3(1), dim3(64), 0, stream>>>(sums, out);
}

// Round 2
// 5277.061 us; speedup vs baseline: 1.6916x; 1.6916x over previous
//
#include <hip/hip_runtime.h>
#include <math.h>

// forecastRNN on MI355X: bf16 MFMA rewrite (m97-style 128x128 tile,
// global_load_lds width-16, 16x16x32 bf16 MFMA, fused epilogues).
// HID padded 1000->1024 with zero rows/cols so all GEMM dims are
// multiples of 128 (M/N) and 32 (K); pad outputs forced to 0 in epilogue.

typedef unsigned short ushort_t;
typedef __attribute__((ext_vector_type(8))) short short8;
typedef __attribute__((ext_vector_type(4))) float f32x4;

#define BB 512
#define TT 65
#define TN 64
#define FF 512
#define HD 1000
#define HDP 1024
#define EPSBN 1e-5f
#define BF (BB*FF)          // 262144
#define MALL (BB*TN)        // 32768
#define CH 4
#define CM (MALL/CH)        // 8192

__device__ __forceinline__ ushort_t f2bf(float f) {
    union { float f; unsigned u; } v; v.f = f;
    unsigned r = v.u + 0x7FFFu + ((v.u >> 16) & 1u);
    return (ushort_t)(r >> 16);
}

// ---------------------------------------------------------------------------
// MFMA GEMM: C[M,N] = A[M,K] @ W[N,K]^T (+ optional second pass A2@W2^T),
// NT layout, bf16 in / fp32 accumulate. 128x128 tile, 256 thr = 4 waves,
// each wave owns a 64x64 quadrant as 4x4 MFMA 16x16 tiles. BK=32.
// epi: 0 out_f32 = acc + p1 + p2                         (XW precompute)
//      1 out_bf16 = tanh(acc + aux[m,n])                 (recurrence step)
//      2 out_bf16 = BN(acc) (0 for n>=Nreal)             (autoenc layers)
//      3 out_bf16 = tanh(acc + p1 + p2)                  (decode cell, dual)
//      4 out_f32 = BN(acc), out2_bf16 = same             (decode L3)
//      5 BN(acc): tau<63 -> loss1 partial; tau==63 -> seed bf16 (autoenc L3)
// ---------------------------------------------------------------------------
__global__ __launch_bounds__(256)
void mfma_gemm(const ushort_t* __restrict__ A, long a_rs,
               const ushort_t* __restrict__ A2, long a2_rs,
               const ushort_t* __restrict__ W,
               const ushort_t* __restrict__ W2,
               int K, int K2, int Nreal,
               void* __restrict__ outv, long o_rs,
               const float* __restrict__ aux, long aux_rs,
               int epi, int mbase,
               const float* __restrict__ p1, const float* __restrict__ p2,
               const float* __restrict__ rm, const float* __restrict__ rv,
               const float* __restrict__ gg, const float* __restrict__ be,
               ushort_t* __restrict__ out2,
               float* __restrict__ sums)
{
    __shared__ ushort_t As[128 * 32];
    __shared__ ushort_t Bs[128 * 32];
    __shared__ float red[256];

    const int tid  = threadIdx.x;
    const int wave = tid >> 6, lane = tid & 63;
    const int wm = wave >> 1, wn = wave & 1;
    const int tileM = blockIdx.y * 128, tileN = blockIdx.x * 128;

    f32x4 acc[4][4] = {};

    const int srow = lane >> 2;          // 0..15: row within 16-row group
    const int skb  = (lane & 3) * 8;     // k-elem offset 0/8/16/24 (16B lanes)

    const int npass = A2 ? 2 : 1;
    for (int pass = 0; pass < npass; ++pass) {
        const ushort_t* Ap = pass ? A2 : A;
        const ushort_t* Wp = pass ? W2 : W;
        const long ars = pass ? a2_rs : a_rs;
        const int Kc = pass ? K2 : K;
        for (int kt = 0; kt < Kc; kt += 32) {
            __syncthreads();
#pragma unroll
            for (int s = 0; s < 2; ++s) {
                const int instr = wave * 2 + s;          // 0..7 (16 rows each)
                const int row = instr * 16 + srow;
                const ushort_t* ga = Ap + (size_t)(tileM + row) * ars + kt + skb;
                const ushort_t* gb = Wp + (size_t)(tileN + row) * (size_t)Kc + kt + skb;
                __builtin_amdgcn_global_load_lds(
                    (const __attribute__((address_space(1))) unsigned int*)ga,
                    (__attribute__((address_space(3))) unsigned int*)&As[instr * 512],
                    16, 0, 0);
                __builtin_amdgcn_global_load_lds(
                    (const __attribute__((address_space(1))) unsigned int*)gb,
                    (__attribute__((address_space(3))) unsigned int*)&Bs[instr * 512],
                    16, 0, 0);
            }
            __syncthreads();
            const int lr = lane & 15;
            const int lk = (lane >> 4) * 8;
            short8 af[4], bfr[4];
#pragma unroll
            for (int i = 0; i < 4; ++i)
                af[i] = *(const short8*)&As[(wm * 64 + i * 16 + lr) * 32 + lk];
#pragma unroll
            for (int j = 0; j < 4; ++j)
                bfr[j] = *(const short8*)&Bs[(wn * 64 + j * 16 + lr) * 32 + lk];
#pragma unroll
            for (int i = 0; i < 4; ++i)
#pragma unroll
                for (int j = 0; j < 4; ++j)
                    acc[i][j] = __builtin_amdgcn_mfma_f32_16x16x32_bf16(
                        af[i], bfr[j], acc[i][j], 0, 0, 0);
        }
    }

    // epilogue: C/D layout col = lane&15, row = (lane>>4)*4 + reg
    const int lr = lane & 15;
    const int rquad = (lane >> 4) * 4;
    float lsum = 0.f;
#pragma unroll
    for (int i = 0; i < 4; ++i) {
#pragma unroll
        for (int r = 0; r < 4; ++r) {
            const int grow = tileM + wm * 64 + i * 16 + rquad + r;
#pragma unroll
            for (int j = 0; j < 4; ++j) {
                const int gcol = tileN + wn * 64 + j * 16 + lr;
                const float v = acc[i][j][r];
                if (epi == 0) {
                    ((float*)outv)[(size_t)grow * o_rs + gcol] = v + p1[gcol] + p2[gcol];
                } else if (epi == 1) {
                    const float t = tanhf(v + aux[(size_t)grow * aux_rs + gcol]);
                    ((ushort_t*)outv)[(size_t)grow * o_rs + gcol] = f2bf(t);
                } else if (epi == 2) {
                    float o = 0.f;
                    if (gcol < Nreal) {
                        const float s = gg[gcol] * rsqrtf(rv[gcol] + EPSBN);
                        o = (v + p1[gcol] - rm[gcol]) * s + be[gcol];
                    }
                    ((ushort_t*)outv)[(size_t)grow * o_rs + gcol] = f2bf(o);
                } else if (epi == 3) {
                    const float t = tanhf(v + p1[gcol] + p2[gcol]);
                    ((ushort_t*)outv)[(size_t)grow * o_rs + gcol] = f2bf(t);
                } else if (epi == 4) {
                    const float s = gg[gcol] * rsqrtf(rv[gcol] + EPSBN);
                    const float o = (v + p1[gcol] - rm[gcol]) * s + be[gcol];
                    ((float*)outv)[(size_t)grow * o_rs + gcol] = o;
                    out2[(size_t)grow * o_rs + gcol] = f2bf(o);
                } else { // epi 5
                    const float s = gg[gcol] * rsqrtf(rv[gcol] + EPSBN);
                    const float o = (v + p1[gcol] - rm[gcol]) * s + be[gcol];
                    const int gm = mbase + grow;
                    const int b = gm >> 6, tau = gm & 63;
                    if (tau < 63) {
                        const float d = o - aux[((size_t)b * TT + tau + 1) * FF + gcol];
                        lsum += d * d;
                    } else {
                        out2[(size_t)b * FF + gcol] = f2bf(o);
                    }
                }
            }
        }
    }
    if (epi == 5) {
        red[tid] = lsum;
        __syncthreads();
        for (int o = 128; o > 0; o >>= 1) {
            if (tid < o) red[tid] += red[tid + o];
            __syncthreads();
        }
        if (tid == 0) atomicAdd(&sums[0], red[0]);
    }
}

// convert x[:, :64, :] fp32 -> bf16 (B,64,F) contiguous
__global__ void conv_x(const float* __restrict__ x, ushort_t* __restrict__ xb)
{
    const int i = blockIdx.x * blockDim.x + threadIdx.x;
    if (i < MALL * FF / 4) {
        const int e = i * 4;
        const int m = e >> 9;            // row = b*64 + t
        const int f = e & (FF - 1);
        const int b = m >> 6, t = m & 63;
        const float4 v = *(const float4*)&x[((size_t)b * TT + t) * FF + f];
        unsigned r0 = (unsigned)f2bf(v.x) | ((unsigned)f2bf(v.y) << 16);
        unsigned r1 = (unsigned)f2bf(v.z) | ((unsigned)f2bf(v.w) << 16);
        *(uint2*)&xb[e] = make_uint2(r0, r1);
    }
}

// convert + zero-pad weight matrix (Nsrc,Ksrc) fp32 -> (Npad,Kpad) bf16
__global__ void conv_w(const float* __restrict__ src, ushort_t* __restrict__ dst,
                       int Nsrc, int Ksrc, int Npad, int Kpad)
{
    const int i = blockIdx.x * blockDim.x + threadIdx.x;
    if (i < Npad * Kpad) {
        const int n = i / Kpad, k = i - n * Kpad;
        const float v = (n < Nsrc && k < Ksrc) ? src[(size_t)n * Ksrc + k] : 0.f;
        dst[i] = f2bf(v);
    }
}

// t=0: hs[b,0,:] = tanh(XW[b,0,:]) (bf16); zero loss sums
__global__ void tanh0_init(const float* __restrict__ xw, ushort_t* __restrict__ hs,
                           float* __restrict__ sums)
{
    const int i = blockIdx.x * blockDim.x + threadIdx.x;
    if (i == 0) { sums[0] = 0.f; sums[1] = 0.f; }
    if (i < BF) {
        const int b = i >> 9, f = i & (FF - 1);
        const size_t idx = (size_t)b * (TN * FF) + f;
        hs[idx] = f2bf(tanhf(xw[idx]));
    }
}

// gather x_pred by per-batch gap; write d_out; accumulate loss2 sum
__global__ void gather_kernel(const float* __restrict__ xgaps,
                              const int* __restrict__ tgap,
                              const float* __restrict__ x,
                              float* __restrict__ out,
                              float* __restrict__ sums)
{
    const int i = blockIdx.x * blockDim.x + threadIdx.x;
    float s = 0.f;
    if (i < BF) {
        const int b = i >> 9, f = i & (FF - 1);
        const int g = tgap[b] - 1;
        const float v = xgaps[((size_t)g * BB + b) * FF + f];
        out[i] = v;
        const float d = v - x[((size_t)b * TT + (TT - 1)) * FF + f];
        s = d * d;
    }
    __shared__ float red[256];
    red[threadIdx.x] = s;
    __syncthreads();
    for (int o = 128; o > 0; o >>= 1) {
        if (threadIdx.x < o) red[threadIdx.x] += red[threadIdx.x + o];
        __syncthreads();
    }
    if (threadIdx.x == 0) atomicAdd(&sums[1], red[0]);
}

__global__ void finalize_kernel(const float* __restrict__ sums,
                                float* __restrict__ out)
{
    if (threadIdx.x == 0 && blockIdx.x == 0) {
        const double n1 = 63.0 * 512.0 * 512.0;
        const double n2 = 512.0 * 512.0;
        out[BF] = (float)((double)sums[0] / (n1 * n1) +
                          (double)sums[1] / (n2 * n2));
    }
}

extern "C" void kernel_launch(void* const* d_in, const int* in_sizes, int n_in,
                              void* d_out, int out_size, void* d_ws, size_t ws_size,
                              hipStream_t stream)
{
    const float* x    = (const float*)d_in[0];
    const int*   tgap = (const int*)d_in[1];
    const float* W_ih = (const float*)d_in[2];
    const float* W_hh = (const float*)d_in[3];
    const float* b_ih = (const float*)d_in[4];
    const float* b_hh = (const float*)d_in[5];
    const float* W1 = (const float*)d_in[6];
    const float* b1 = (const float*)d_in[7];
    const float* g1 = (const float*)d_in[8];
    const float* be1 = (const float*)d_in[9];
    const float* rm1 = (const float*)d_in[10];
    const float* rv1 = (const float*)d_in[11];
    const float* W2 = (const float*)d_in[12];
    const float* b2 = (const float*)d_in[13];
    const float* g2 = (const float*)d_in[14];
    const float* be2 = (const float*)d_in[15];
    const float* rm2 = (const float*)d_in[16];
    const float* rv2 = (const float*)d_in[17];
    const float* W3 = (const float*)d_in[18];
    const float* b3 = (const float*)d_in[19];
    const float* g3 = (const float*)d_in[20];
    const float* be3 = (const float*)d_in[21];
    const float* rm3 = (const float*)d_in[22];
    const float* rv3 = (const float*)d_in[23];
    float* out = (float*)d_out;

    // workspace carve-up (64B aligned), ~201 MB total
    char* p = (char*)d_ws;
    auto take = [&](size_t bytes) -> char* {
        char* r = p; p += (bytes + 63) & ~(size_t)63; return r;
    };
    float*    XWbuf = (float*)take((size_t)MALL * FF * 4);      // 67.1 MB
    ushort_t* hs    = (ushort_t*)take((size_t)MALL * FF * 2);   // 33.5 MB
    ushort_t* xbf   = (ushort_t*)take((size_t)MALL * FF * 2);   // 33.5 MB
    ushort_t* z1    = (ushort_t*)take((size_t)CM * HDP * 2);    // 16.8 MB
    ushort_t* z2    = (ushort_t*)take((size_t)CM * HDP * 2);    // 16.8 MB
    float*    xg    = (float*)take((size_t)16 * BF * 4);        // 16.8 MB
    ushort_t* xgb   = (ushort_t*)take((size_t)16 * BF * 2);     //  8.4 MB
    ushort_t* seed  = (ushort_t*)take((size_t)BF * 2);
    ushort_t* hdec  = (ushort_t*)take((size_t)2 * BF * 2);
    ushort_t* zd1   = (ushort_t*)take((size_t)BB * HDP * 2);
    ushort_t* zd2   = (ushort_t*)take((size_t)BB * HDP * 2);
    ushort_t* Wihb  = (ushort_t*)take((size_t)FF * FF * 2);
    ushort_t* Whhb  = (ushort_t*)take((size_t)FF * FF * 2);
    ushort_t* W1b   = (ushort_t*)take((size_t)HDP * FF * 2);
    ushort_t* W2b   = (ushort_t*)take((size_t)HDP * HDP * 2);
    ushort_t* W3b   = (ushort_t*)take((size_t)FF * HDP * 2);
    float*    sums  = (float*)take(2 * 4);

    const dim3 blk(256);

    // 0) conversions
    conv_x<<<dim3(MALL * FF / 4 / 256), blk, 0, stream>>>(x, xbf);
    conv_w<<<dim3((FF * FF + 255) / 256), blk, 0, stream>>>(W_ih, Wihb, FF, FF, FF, FF);
    conv_w<<<dim3((FF * FF + 255) / 256), blk, 0, stream>>>(W_hh, Whhb, FF, FF, FF, FF);
    conv_w<<<dim3((HDP * FF + 255) / 256), blk, 0, stream>>>(W1, W1b, HD, FF, HDP, FF);
    conv_w<<<dim3((HDP * HDP + 255) / 256), blk, 0, stream>>>(W2, W2b, HD, HD, HDP, HDP);
    conv_w<<<dim3((FF * HDP + 255) / 256), blk, 0, stream>>>(W3, W3b, FF, HD, FF, HDP);

    // 1) XW = x @ W_ih^T + b_ih + b_hh -> fp32 XWbuf (M=32768, N=512, K=512)
    mfma_gemm<<<dim3(FF / 128, MALL / 128), blk, 0, stream>>>(
        xbf, FF, nullptr, 0, Wihb, nullptr, FF, 0, FF,
        XWbuf, FF, nullptr, 0, 0, 0,
        b_ih, b_hh, nullptr, nullptr, nullptr, nullptr, nullptr, nullptr);

    // 2) t=0 + zero sums
    tanh0_init<<<dim3(BF / 256), blk, 0, stream>>>(XWbuf, hs, sums);

    // 3) recurrence t=1..63: hs_t = tanh(h_{t-1} @ W_hh^T + XW_t)  (M=N=K=512)
    for (int t = 1; t < TN; ++t) {
        mfma_gemm<<<dim3(FF / 128, BB / 128), blk, 0, stream>>>(
            hs + (size_t)(t - 1) * FF, (long)TN * FF, nullptr, 0,
            Whhb, nullptr, FF, 0, FF,
            hs + (size_t)t * FF, (long)TN * FF,
            XWbuf + (size_t)t * FF, (long)TN * FF, 1, 0,
            nullptr, nullptr, nullptr, nullptr, nullptr, nullptr, nullptr, nullptr);
    }

    // 4) autoenc over 32768 rows in 4 chunks of 8192
    for (int c = 0; c < CH; ++c) {
        const ushort_t* Ac = hs + (size_t)c * CM * FF;
        // L1: z1 = BN1(h @ W1^T + b1)   (8192 x 1024, K=512)
        mfma_gemm<<<dim3(HDP / 128, CM / 128), blk, 0, stream>>>(
            Ac, FF, nullptr, 0, W1b, nullptr, FF, 0, HD,
            z1, HDP, nullptr, 0, 2, 0,
            b1, nullptr, rm1, rv1, g1, be1, nullptr, nullptr);
        // L2: z2 = BN2(z1 @ W2^T + b2)  (8192 x 1024, K=1024)
        mfma_gemm<<<dim3(HDP / 128, CM / 128), blk, 0, stream>>>(
            z1, HDP, nullptr, 0, W2b, nullptr, HDP, 0, HD,
            z2, HDP, nullptr, 0, 2, 0,
            b2, nullptr, rm2, rv2, g2, be2, nullptr, nullptr);
        // L3: y = BN3(z2 @ W3^T + b3) -> loss1 partial + seed (tau==63)
        mfma_gemm<<<dim3(FF / 128, CM / 128), blk, 0, stream>>>(
            z2, HDP, nullptr, 0, W3b, nullptr, HDP, 0, FF,
            nullptr, 0, x, 0, 5, c * CM,
            b3, nullptr, rm3, rv3, g3, be3, seed, sums);
    }

    // 5) decode: 16 autoregressive steps (M=512)
    for (int g = 0; g < 16; ++g) {
        const ushort_t* xprev = g ? (xgb + (size_t)(g - 1) * BF) : seed;
        const ushort_t* hprev = g ? (hdec + (size_t)((g - 1) & 1) * BF)
                                  : (hs + (size_t)(TN - 1) * FF);
        const long h_rs = g ? (long)FF : (long)TN * FF;
        ushort_t* hnew = hdec + (size_t)(g & 1) * BF;
        // cell: h2 = tanh(x̂@W_ih^T + ĥ@W_hh^T + b_ih + b_hh)
        mfma_gemm<<<dim3(FF / 128, BB / 128), blk, 0, stream>>>(
            xprev, FF, hprev, h_rs, Wihb, Whhb, FF, FF, FF,
            hnew, FF, nullptr, 0, 3, 0,
            b_ih, b_hh, nullptr, nullptr, nullptr, nullptr, nullptr, nullptr);
        // L1
        mfma_gemm<<<dim3(HDP / 128, BB / 128), blk, 0, stream>>>(
            hnew, FF, nullptr, 0, W1b, nullptr, FF, 0, HD,
            zd1, HDP, nullptr, 0, 2, 0,
            b1, nullptr, rm1, rv1, g1, be1, nullptr, nullptr);
        // L2
        mfma_gemm<<<dim3(HDP / 128, BB / 128), blk, 0, stream>>>(
            zd1, HDP, nullptr, 0, W2b, nullptr, HDP, 0, HD,
            zd2, HDP, nullptr, 0, 2, 0,
            b2, nullptr, rm2, rv2, g2, be2, nullptr, nullptr);
        // L3 -> xg (fp32) + xgb (bf16)
        mfma_gemm<<<dim3(FF / 128, BB / 128), blk, 0, stream>>>(
            zd2, HDP, nullptr, 0, W3b, nullptr, HDP, 0, FF,
            xg + (size_t)g * BF, FF, nullptr, 0, 4, 0,
            b3, nullptr, rm3, rv3, g3, be3, xgb + (size_t)g * BF, nullptr);
    }

    // 6) gather x_pred + loss2; 7) finalize
    gather_kernel<<<dim3(BF / 256), blk, 0, stream>>>(xg, tgap, x, out, sums);
    finalize_kernel<<<dim3(1), dim3(64), 0, stream>>>(sums, out);
}

// Round 3
// 3980.322 us; speedup vs baseline: 2.2427x; 1.3258x over previous
//
#include <hip/hip_runtime.h>
#include <math.h>

// forecastRNN on MI355X, round 3: persistent kernels for the two serial
// chains. Recurrence: 32 blocks, batch-split, NO cross-block sync (batch rows
// are independent), h in LDS, W_hh streamed from L2 per step. Decode: 64
// blocks, 16 steps x 4 stages, hand-rolled device-scope grid barrier.
// Large GEMMs (XW precompute, autoenc) stay as mfma_gemm launches.

typedef unsigned short ushort_t;
typedef __attribute__((ext_vector_type(8))) short short8;
typedef __attribute__((ext_vector_type(4))) float f32x4;

#define BB 512
#define TT 65
#define TN 64
#define FF 512
#define HD 1000
#define HDP 1024
#define EPSBN 1e-5f
#define BF (BB*FF)          // 262144
#define MALL (BB*TN)        // 32768
#define CH 4
#define CM (MALL/CH)        // 8192
#define HPAD 520            // hbuf row stride (ushorts): 1040 B = 65*16, 2-way banks

__device__ __forceinline__ ushort_t f2bf(float f) {
    union { float f; unsigned u; } v; v.f = f;
    unsigned r = v.u + 0x7FFFu + ((v.u >> 16) & 1u);
    return (ushort_t)(r >> 16);
}

__device__ __forceinline__ void ld16(const ushort_t* g, ushort_t* l) {
    __builtin_amdgcn_global_load_lds(
        (const __attribute__((address_space(1))) unsigned*)g,
        (__attribute__((address_space(3))) unsigned*)l, 16, 0, 0);
}

// ---------------------------------------------------------------------------
// Large-GEMM kernel (XW precompute + autoenc), 128x128 tile, BK=32.
// epi: 0 out_f32 = acc + p1 + p2
//      2 out_bf16 = BN(acc) (0 for col >= Nreal)
//      5 BN(acc): tau<63 -> loss1 partial vs aux(=x); tau==63 -> seed bf16
// ---------------------------------------------------------------------------
__global__ __launch_bounds__(256)
void mfma_gemm(const ushort_t* __restrict__ A, long a_rs,
               const ushort_t* __restrict__ W, int K, int Nreal,
               void* __restrict__ outv, long o_rs,
               const float* __restrict__ aux, int epi, int mbase,
               const float* __restrict__ p1, const float* __restrict__ p2,
               const float* __restrict__ rm, const float* __restrict__ rv,
               const float* __restrict__ gg, const float* __restrict__ be,
               ushort_t* __restrict__ out2, float* __restrict__ sums)
{
    __shared__ ushort_t As[128 * 32];
    __shared__ ushort_t Bs[128 * 32];
    __shared__ float red[256];

    const int tid  = threadIdx.x;
    const int wave = tid >> 6, lane = tid & 63;
    const int wm = wave >> 1, wn = wave & 1;
    const int tileM = blockIdx.y * 128, tileN = blockIdx.x * 128;

    f32x4 acc[4][4] = {};
    const int srow = lane >> 2;
    const int skb  = (lane & 3) * 8;

    for (int kt = 0; kt < K; kt += 32) {
        __syncthreads();
#pragma unroll
        for (int s = 0; s < 2; ++s) {
            const int instr = wave * 2 + s;
            const int row = instr * 16 + srow;
            ld16(A + (size_t)(tileM + row) * a_rs + kt + skb, &As[instr * 512]);
            ld16(W + (size_t)(tileN + row) * (size_t)K + kt + skb, &Bs[instr * 512]);
        }
        __syncthreads();
        const int lr = lane & 15;
        const int lk = (lane >> 4) * 8;
        short8 af[4], bfr[4];
#pragma unroll
        for (int i = 0; i < 4; ++i)
            af[i] = *(const short8*)&As[(wm * 64 + i * 16 + lr) * 32 + lk];
#pragma unroll
        for (int j = 0; j < 4; ++j)
            bfr[j] = *(const short8*)&Bs[(wn * 64 + j * 16 + lr) * 32 + lk];
#pragma unroll
        for (int i = 0; i < 4; ++i)
#pragma unroll
            for (int j = 0; j < 4; ++j)
                acc[i][j] = __builtin_amdgcn_mfma_f32_16x16x32_bf16(
                    af[i], bfr[j], acc[i][j], 0, 0, 0);
    }

    const int lr = lane & 15;
    const int rquad = (lane >> 4) * 4;
    float lsum = 0.f;
#pragma unroll
    for (int i = 0; i < 4; ++i) {
#pragma unroll
        for (int r = 0; r < 4; ++r) {
            const int grow = tileM + wm * 64 + i * 16 + rquad + r;
#pragma unroll
            for (int j = 0; j < 4; ++j) {
                const int gcol = tileN + wn * 64 + j * 16 + lr;
                const float v = acc[i][j][r];
                if (epi == 0) {
                    ((float*)outv)[(size_t)grow * o_rs + gcol] = v + p1[gcol] + p2[gcol];
                } else if (epi == 2) {
                    float o = 0.f;
                    if (gcol < Nreal) {
                        const float s = gg[gcol] * rsqrtf(rv[gcol] + EPSBN);
                        o = (v + p1[gcol] - rm[gcol]) * s + be[gcol];
                    }
                    ((ushort_t*)outv)[(size_t)grow * o_rs + gcol] = f2bf(o);
                } else { // epi 5
                    const float s = gg[gcol] * rsqrtf(rv[gcol] + EPSBN);
                    const float o = (v + p1[gcol] - rm[gcol]) * s + be[gcol];
                    const int gm = mbase + grow;
                    const int b = gm >> 6, tau = gm & 63;
                    if (tau < 63) {
                        const float d = o - aux[((size_t)b * TT + tau + 1) * FF + gcol];
                        lsum += d * d;
                    } else {
                        out2[(size_t)b * FF + gcol] = f2bf(o);
                    }
                }
            }
        }
    }
    if (epi == 5) {
        red[tid] = lsum;
        __syncthreads();
        for (int o = 128; o > 0; o >>= 1) {
            if (tid < o) red[tid] += red[tid + o];
            __syncthreads();
        }
        if (tid == 0) atomicAdd(&sums[0], red[0]);
    }
}

// ---------------------------------------------------------------------------
// Persistent recurrence: 32 blocks x 16 batch rows. No cross-block deps.
// hs[b*64+t, :] written for all t. h kept in LDS (bf16); W_hh streamed.
// ---------------------------------------------------------------------------
__global__ __launch_bounds__(256)
void rnn_persistent(const ushort_t* __restrict__ Whhb,
                    const float* __restrict__ XW,
                    ushort_t* __restrict__ hs)
{
    __shared__ ushort_t hbuf[16 * HPAD];
    __shared__ ushort_t Ws[2 * 16384];   // [buf][kgrp4][n512][8]
    const int tid = threadIdx.x, wave = tid >> 6, lane = tid & 63;
    const int b0 = blockIdx.x * 16;

    // t = 0: h = tanh(XW_0)
    for (int it = 0; it < 32; ++it) {
        const int idx = it * 256 + tid;
        const int row = idx >> 9, col = idx & 511;
        const size_t gidx = ((size_t)(b0 + row) * TN) * FF + col;
        const ushort_t hb = f2bf(tanhf(XW[gidx]));
        hbuf[row * HPAD + col] = hb;
        hs[gidx] = hb;
    }
    __syncthreads();

    f32x4 acc[8];
    for (int t = 1; t < TN; ++t) {
        if (t == 1) {
            // prologue prefetch chunk 0 -> buf 0
#pragma unroll
            for (int s = 0; s < 8; ++s) {
                const int linear = s * 4096 + wave * 1024;   // bytes
                const int kgrp = linear >> 13;
                const int nb = (linear & 8191) >> 4;
                ld16(Whhb + (size_t)(nb + lane) * FF + kgrp * 8,
                     Ws + (linear >> 1));
            }
        }
#pragma unroll
        for (int j = 0; j < 8; ++j) acc[j] = (f32x4){0.f, 0.f, 0.f, 0.f};

        for (int kc = 0; kc < 16; ++kc) {
            __syncthreads();   // chunk kc landed
            if (kc < 15) {
                const int kt = (kc + 1) * 32;
                const int buf = (kc + 1) & 1;
#pragma unroll
                for (int s = 0; s < 8; ++s) {
                    const int linear = s * 4096 + wave * 1024;
                    const int kgrp = linear >> 13;
                    const int nb = (linear & 8191) >> 4;
                    ld16(Whhb + (size_t)(nb + lane) * FF + kt + kgrp * 8,
                         Ws + buf * 16384 + (linear >> 1));
                }
            }
            const short8 af = *(const short8*)
                &hbuf[(lane & 15) * HPAD + kc * 32 + (lane >> 4) * 8];
            const int wb = (kc & 1) * 16384 + (lane >> 4) * 4096;
#pragma unroll
            for (int j = 0; j < 8; ++j) {
                const short8 bf = *(const short8*)
                    &Ws[wb + (wave * 128 + j * 16 + (lane & 15)) * 8];
                acc[j] = __builtin_amdgcn_mfma_f32_16x16x32_bf16(af, bf, acc[j], 0, 0, 0);
            }
        }
        __syncthreads();       // all hbuf/Ws reads done
        if (t < 63) {
            // prefetch chunk 0 of next step into buf 0 (overlaps epilogue)
#pragma unroll
            for (int s = 0; s < 8; ++s) {
                const int linear = s * 4096 + wave * 1024;
                const int kgrp = linear >> 13;
                const int nb = (linear & 8191) >> 4;
                ld16(Whhb + (size_t)(nb + lane) * FF + kgrp * 8,
                     Ws + (linear >> 1));
            }
        }
#pragma unroll
        for (int j = 0; j < 8; ++j) {
            const int gcol = wave * 128 + j * 16 + (lane & 15);
#pragma unroll
            for (int rr = 0; rr < 4; ++rr) {
                const int grow = (lane >> 4) * 4 + rr;
                const size_t gidx = ((size_t)(b0 + grow) * TN + t) * FF + gcol;
                const ushort_t hb = f2bf(tanhf(acc[j][rr] + XW[gidx]));
                hbuf[grow * HPAD + gcol] = hb;
                hs[gidx] = hb;
            }
        }
        __syncthreads();       // hbuf updated before next step's reads
    }
}

// ---------------------------------------------------------------------------
// Grid barrier (device scope, 64 co-resident blocks)
// ---------------------------------------------------------------------------
__device__ __forceinline__ void gbar(unsigned* cnt, unsigned target) {
    __syncthreads();
    if (threadIdx.x == 0) {
        __hip_atomic_fetch_add(cnt, 1u, __ATOMIC_ACQ_REL, __HIP_MEMORY_SCOPE_AGENT);
        while (__hip_atomic_load(cnt, __ATOMIC_ACQUIRE, __HIP_MEMORY_SCOPE_AGENT) < target) {
            __builtin_amdgcn_s_sleep(2);
        }
    }
    __syncthreads();
}

// ---------------------------------------------------------------------------
// One decode GEMM stage: rows [tileM,tileM+64) x cols [tileN,tileN+NC).
// A (and optional A2) bf16 [512 x K], W bf16 [N x K]. BK=32, double-buffered.
// epi: 0 tanh(acc+p1+p2) -> obf ; 1 BN -> obf (0 pad) ; 2 BN -> of32 + obf
// ---------------------------------------------------------------------------
template <int NC>
__device__ __forceinline__ void dec_stage(
    const ushort_t* __restrict__ A, long a_rs,
    const ushort_t* __restrict__ A2, long a2_rs,
    const ushort_t* __restrict__ W, const ushort_t* __restrict__ W2,
    int Kc, int K2c, int tileM, int tileN, int Nreal, int epi,
    ushort_t* __restrict__ obf, float* __restrict__ of32, long o_rs,
    const float* __restrict__ p1, const float* __restrict__ p2,
    const float* __restrict__ rm, const float* __restrict__ rvv,
    const float* __restrict__ gg, const float* __restrict__ be,
    ushort_t* At, ushort_t* Wt)
{
    const int tid = threadIdx.x, wave = tid >> 6, lane = tid & 63;
    const int nch1 = Kc >> 5;
    const int nch = nch1 + (A2 ? (K2c >> 5) : 0);
    constexpr int NT = NC >> 4;
    f32x4 acc[NT];
#pragma unroll
    for (int j = 0; j < NT; ++j) acc[j] = (f32x4){0.f, 0.f, 0.f, 0.f};

    auto issue = [&](int kc, int buf) {
        const bool pass = (kc >= nch1);
        const ushort_t* Ap = pass ? A2 : A;
        const ushort_t* Wp = pass ? W2 : W;
        const long ars = pass ? a2_rs : a_rs;
        const int KK = pass ? K2c : Kc;
        const int kt = (pass ? kc - nch1 : kc) * 32;
        // A tile: [kgrp=wave][row=lane][8]
        ld16(Ap + (size_t)(tileM + lane) * ars + kt + wave * 8,
             At + buf * 2048 + wave * 512);
        // W tile
        if (NC == 64) {
            ld16(Wp + (size_t)(tileN + lane) * KK + kt + wave * 8,
                 Wt + buf * 4096 + wave * 512);
        } else {
#pragma unroll
            for (int s = 0; s < 2; ++s) {
                const int kgrp = s * 2 + (wave >> 1);
                const int nb = (wave & 1) * 64;
                ld16(Wp + (size_t)(tileN + nb + lane) * KK + kt + kgrp * 8,
                     Wt + buf * 4096 + s * 2048 + wave * 512);
            }
        }
    };

    issue(0, 0);
    for (int kc = 0; kc < nch; ++kc) {
        __syncthreads();
        if (kc + 1 < nch) issue(kc + 1, (kc + 1) & 1);
        const int ab = (kc & 1) * 2048 + (lane >> 4) * 512;
        const int wb = (kc & 1) * 4096 + (lane >> 4) * (NC * 8);
        const short8 af = *(const short8*)&At[ab + (wave * 16 + (lane & 15)) * 8];
#pragma unroll
        for (int j = 0; j < NT; ++j) {
            const short8 bf = *(const short8*)&Wt[wb + (j * 16 + (lane & 15)) * 8];
            acc[j] = __builtin_amdgcn_mfma_f32_16x16x32_bf16(af, bf, acc[j], 0, 0, 0);
        }
    }
    // epilogue
#pragma unroll
    for (int j = 0; j < NT; ++j) {
        const int gcol = tileN + j * 16 + (lane & 15);
#pragma unroll
        for (int rr = 0; rr < 4; ++rr) {
            const int grow = tileM + wave * 16 + (lane >> 4) * 4 + rr;
            const float v = acc[j][rr];
            if (epi == 0) {
                obf[(size_t)grow * o_rs + gcol] = f2bf(tanhf(v + p1[gcol] + p2[gcol]));
            } else if (epi == 1) {
                float o = 0.f;
                if (gcol < Nreal) {
                    const float s = gg[gcol] * rsqrtf(rvv[gcol] + EPSBN);
                    o = (v + p1[gcol] - rm[gcol]) * s + be[gcol];
                }
                obf[(size_t)grow * o_rs + gcol] = f2bf(o);
            } else {
                const float s = gg[gcol] * rsqrtf(rvv[gcol] + EPSBN);
                const float o = (v + p1[gcol] - rm[gcol]) * s + be[gcol];
                of32[(size_t)grow * o_rs + gcol] = o;
                obf[(size_t)grow * o_rs + gcol] = f2bf(o);
            }
        }
    }
}

// ---------------------------------------------------------------------------
// Persistent decode: 64 blocks (8 row-groups x 8 col-groups), 16 steps x
// 4 stages, grid barrier between stages.
// ---------------------------------------------------------------------------
__global__ __launch_bounds__(256)
void decode_persistent(const ushort_t* __restrict__ seed,
                       const ushort_t* __restrict__ hs,
                       const ushort_t* __restrict__ Wih,
                       const ushort_t* __restrict__ Whh,
                       const ushort_t* __restrict__ W1b,
                       const ushort_t* __restrict__ W2b,
                       const ushort_t* __restrict__ W3b,
                       ushort_t* __restrict__ hdec,
                       ushort_t* __restrict__ z1, ushort_t* __restrict__ z2,
                       float* __restrict__ xg, ushort_t* __restrict__ xgb,
                       unsigned* __restrict__ cnt,
                       const float* __restrict__ b_ih, const float* __restrict__ b_hh,
                       const float* __restrict__ b1, const float* __restrict__ rm1,
                       const float* __restrict__ rv1, const float* __restrict__ g1,
                       const float* __restrict__ be1,
                       const float* __restrict__ b2, const float* __restrict__ rm2,
                       const float* __restrict__ rv2, const float* __restrict__ g2,
                       const float* __restrict__ be2,
                       const float* __restrict__ b3, const float* __restrict__ rm3,
                       const float* __restrict__ rv3, const float* __restrict__ g3,
                       const float* __restrict__ be3)
{
    __shared__ ushort_t At[2 * 2048];
    __shared__ ushort_t Wt[2 * 4096];
    const int r = blockIdx.x >> 3, c = blockIdx.x & 7;
    unsigned phase = 0;

    for (int g = 0; g < 16; ++g) {
        const ushort_t* xprev = g ? (xgb + (size_t)(g - 1) * BF) : seed;
        const ushort_t* hprev = g ? (hdec + (size_t)((g - 1) & 1) * BF)
                                  : (hs + (size_t)(TN - 1) * FF);
        const long h_rs = g ? (long)FF : (long)TN * FF;
        ushort_t* hnew = hdec + (size_t)(g & 1) * BF;

        // cell
        dec_stage<64>(xprev, FF, hprev, h_rs, Wih, Whh, FF, FF,
                      r * 64, c * 64, FF, 0, hnew, nullptr, FF,
                      b_ih, b_hh, nullptr, nullptr, nullptr, nullptr, At, Wt);
        gbar(cnt, 64u * (++phase));
        // L1
        dec_stage<128>(hnew, FF, nullptr, 0, W1b, nullptr, FF, 0,
                       r * 64, c * 128, HD, 1, z1, nullptr, HDP,
                       b1, nullptr, rm1, rv1, g1, be1, At, Wt);
        gbar(cnt, 64u * (++phase));
        // L2
        dec_stage<128>(z1, HDP, nullptr, 0, W2b, nullptr, HDP, 0,
                       r * 64, c * 128, HD, 1, z2, nullptr, HDP,
                       b2, nullptr, rm2, rv2, g2, be2, At, Wt);
        gbar(cnt, 64u * (++phase));
        // L3
        dec_stage<64>(z2, HDP, nullptr, 0, W3b, nullptr, HDP, 0,
                      r * 64, c * 64, FF, 2, xgb + (size_t)g * BF,
                      xg + (size_t)g * BF, FF,
                      b3, nullptr, rm3, rv3, g3, be3, At, Wt);
        gbar(cnt, 64u * (++phase));
    }
}

// ---------------------------------------------------------------------------
__global__ void zero_init(float* __restrict__ sums, unsigned* __restrict__ cnt)
{
    if (threadIdx.x == 0 && blockIdx.x == 0) {
        sums[0] = 0.f; sums[1] = 0.f; *cnt = 0u;
    }
}

__global__ void conv_x(const float* __restrict__ x, ushort_t* __restrict__ xb)
{
    const int i = blockIdx.x * blockDim.x + threadIdx.x;
    if (i < MALL * FF / 4) {
        const int e = i * 4;
        const int m = e >> 9;
        const int f = e & (FF - 1);
        const int b = m >> 6, t = m & 63;
        const float4 v = *(const float4*)&x[((size_t)b * TT + t) * FF + f];
        unsigned r0 = (unsigned)f2bf(v.x) | ((unsigned)f2bf(v.y) << 16);
        unsigned r1 = (unsigned)f2bf(v.z) | ((unsigned)f2bf(v.w) << 16);
        *(uint2*)&xb[e] = make_uint2(r0, r1);
    }
}

__global__ void conv_w(const float* __restrict__ src, ushort_t* __restrict__ dst,
                       int Nsrc, int Ksrc, int Npad, int Kpad)
{
    const int i = blockIdx.x * blockDim.x + threadIdx.x;
    if (i < Npad * Kpad) {
        const int n = i / Kpad, k = i - n * Kpad;
        const float v = (n < Nsrc && k < Ksrc) ? src[(size_t)n * Ksrc + k] : 0.f;
        dst[i] = f2bf(v);
    }
}

__global__ void gather_kernel(const float* __restrict__ xgaps,
                              const int* __restrict__ tgap,
                              const float* __restrict__ x,
                              float* __restrict__ out,
                              float* __restrict__ sums)
{
    const int i = blockIdx.x * blockDim.x + threadIdx.x;
    float s = 0.f;
    if (i < BF) {
        const int b = i >> 9, f = i & (FF - 1);
        const int g = tgap[b] - 1;
        const float v = xgaps[((size_t)g * BB + b) * FF + f];
        out[i] = v;
        const float d = v - x[((size_t)b * TT + (TT - 1)) * FF + f];
        s = d * d;
    }
    __shared__ float red[256];
    red[threadIdx.x] = s;
    __syncthreads();
    for (int o = 128; o > 0; o >>= 1) {
        if (threadIdx.x < o) red[threadIdx.x] += red[threadIdx.x + o];
        __syncthreads();
    }
    if (threadIdx.x == 0) atomicAdd(&sums[1], red[0]);
}

__global__ void finalize_kernel(const float* __restrict__ sums,
                                float* __restrict__ out)
{
    if (threadIdx.x == 0 && blockIdx.x == 0) {
        const double n1 = 63.0 * 512.0 * 512.0;
        const double n2 = 512.0 * 512.0;
        out[BF] = (float)((double)sums[0] / (n1 * n1) +
                          (double)sums[1] / (n2 * n2));
    }
}

extern "C" void kernel_launch(void* const* d_in, const int* in_sizes, int n_in,
                              void* d_out, int out_size, void* d_ws, size_t ws_size,
                              hipStream_t stream)
{
    const float* x    = (const float*)d_in[0];
    const int*   tgap = (const int*)d_in[1];
    const float* W_ih = (const float*)d_in[2];
    const float* W_hh = (const float*)d_in[3];
    const float* b_ih = (const float*)d_in[4];
    const float* b_hh = (const float*)d_in[5];
    const float* W1 = (const float*)d_in[6];
    const float* b1 = (const float*)d_in[7];
    const float* g1 = (const float*)d_in[8];
    const float* be1 = (const float*)d_in[9];
    const float* rm1 = (const float*)d_in[10];
    const float* rv1 = (const float*)d_in[11];
    const float* W2 = (const float*)d_in[12];
    const float* b2 = (const float*)d_in[13];
    const float* g2 = (const float*)d_in[14];
    const float* be2 = (const float*)d_in[15];
    const float* rm2 = (const float*)d_in[16];
    const float* rv2 = (const float*)d_in[17];
    const float* W3 = (const float*)d_in[18];
    const float* b3 = (const float*)d_in[19];
    const float* g3 = (const float*)d_in[20];
    const float* be3 = (const float*)d_in[21];
    const float* rm3 = (const float*)d_in[22];
    const float* rv3 = (const float*)d_in[23];
    float* out = (float*)d_out;

    char* p = (char*)d_ws;
    auto take = [&](size_t bytes) -> char* {
        char* r = p; p += (bytes + 63) & ~(size_t)63; return r;
    };
    float*    XWbuf = (float*)take((size_t)MALL * FF * 4);      // 67.1 MB
    ushort_t* hs    = (ushort_t*)take((size_t)MALL * FF * 2);   // 33.5 MB
    ushort_t* xbf   = (ushort_t*)take((size_t)MALL * FF * 2);   // 33.5 MB
    ushort_t* z1    = (ushort_t*)take((size_t)CM * HDP * 2);    // 16.8 MB
    ushort_t* z2    = (ushort_t*)take((size_t)CM * HDP * 2);    // 16.8 MB
    float*    xg    = (float*)take((size_t)16 * BF * 4);        // 16.8 MB
    ushort_t* xgb   = (ushort_t*)take((size_t)16 * BF * 2);     //  8.4 MB
    ushort_t* seed  = (ushort_t*)take((size_t)BF * 2);
    ushort_t* hdec  = (ushort_t*)take((size_t)2 * BF * 2);
    ushort_t* zd1   = (ushort_t*)take((size_t)BB * HDP * 2);
    ushort_t* zd2   = (ushort_t*)take((size_t)BB * HDP * 2);
    ushort_t* Wihb  = (ushort_t*)take((size_t)FF * FF * 2);
    ushort_t* Whhb  = (ushort_t*)take((size_t)FF * FF * 2);
    ushort_t* W1b   = (ushort_t*)take((size_t)HDP * FF * 2);
    ushort_t* W2b   = (ushort_t*)take((size_t)HDP * HDP * 2);
    ushort_t* W3b   = (ushort_t*)take((size_t)FF * HDP * 2);
    float*    sums  = (float*)take(16 * 4);
    unsigned* cnt   = (unsigned*)take(64);

    const dim3 blk(256);

    zero_init<<<dim3(1), dim3(64), 0, stream>>>(sums, cnt);
    conv_x<<<dim3(MALL * FF / 4 / 256), blk, 0, stream>>>(x, xbf);
    conv_w<<<dim3((FF * FF + 255) / 256), blk, 0, stream>>>(W_ih, Wihb, FF, FF, FF, FF);
    conv_w<<<dim3((FF * FF + 255) / 256), blk, 0, stream>>>(W_hh, Whhb, FF, FF, FF, FF);
    conv_w<<<dim3((HDP * FF + 255) / 256), blk, 0, stream>>>(W1, W1b, HD, FF, HDP, FF);
    conv_w<<<dim3((HDP * HDP + 255) / 256), blk, 0, stream>>>(W2, W2b, HD, HD, HDP, HDP);
    conv_w<<<dim3((FF * HDP + 255) / 256), blk, 0, stream>>>(W3, W3b, FF, HD, FF, HDP);

    // 1) XW = x @ W_ih^T + b_ih + b_hh -> fp32
    mfma_gemm<<<dim3(FF / 128, MALL / 128), blk, 0, stream>>>(
        xbf, FF, Wihb, FF, FF, XWbuf, FF, nullptr, 0, 0,
        b_ih, b_hh, nullptr, nullptr, nullptr, nullptr, nullptr, nullptr);

    // 2) recurrence, all 64 steps in one persistent kernel
    rnn_persistent<<<dim3(BB / 16), blk, 0, stream>>>(Whhb, XWbuf, hs);

    // 3) autoenc over 32768 rows in 4 chunks
    for (int c = 0; c < CH; ++c) {
        const ushort_t* Ac = hs + (size_t)c * CM * FF;
        mfma_gemm<<<dim3(HDP / 128, CM / 128), blk, 0, stream>>>(
            Ac, FF, W1b, FF, HD, z1, HDP, nullptr, 2, 0,
            b1, nullptr, rm1, rv1, g1, be1, nullptr, nullptr);
        mfma_gemm<<<dim3(HDP / 128, CM / 128), blk, 0, stream>>>(
            z1, HDP, W2b, HDP, HD, z2, HDP, nullptr, 2, 0,
            b2, nullptr, rm2, rv2, g2, be2, nullptr, nullptr);
        mfma_gemm<<<dim3(FF / 128, CM / 128), blk, 0, stream>>>(
            z2, HDP, W3b, HDP, FF, nullptr, 0, x, 5, c * CM,
            b3, nullptr, rm3, rv3, g3, be3, seed, sums);
    }

    // 4) decode, all 16 steps in one persistent kernel
    decode_persistent<<<dim3(64), blk, 0, stream>>>(
        seed, hs, Wihb, Whhb, W1b, W2b, W3b,
        hdec, zd1, zd2, xg, xgb, cnt,
        b_ih, b_hh,
        b1, rm1, rv1, g1, be1,
        b2, rm2, rv2, g2, be2,
        b3, rm3, rv3, g3, be3);

    // 5) gather + finalize
    gather_kernel<<<dim3(BF / 256), blk, 0, stream>>>(xg, tgap, x, out, sums);
    finalize_kernel<<<dim3(1), dim3(64), 0, stream>>>(sums, out);
}